// Round 3
// baseline (5693.047 us; speedup 1.0000x reference)
//
#include <hip/hip_runtime.h>
#include <cstdint>
#include <cstddef>

#define HID   32
#define TLEN  4096
#define DIN   8
#define DOUT  80

typedef float v2f __attribute__((ext_vector_type(2)));

// sigmoid(x) = 1/(1+2^(-x*log2e)); saturates correctly at +-inf
__device__ __forceinline__ float fsig(float x) {
    float e = __builtin_amdgcn_exp2f(-1.442695041f * x);
    return __builtin_amdgcn_rcpf(1.0f + e);
}
// tanh(x) = 1 - 2/(2^(2x*log2e)+1); exact saturation at +-inf
__device__ __forceinline__ float ftanh(float x) {
    float e = __builtin_amdgcn_exp2f(2.885390082f * x);
    return 1.0f - 2.0f * __builtin_amdgcn_rcpf(e + 1.0f);
}
__device__ __forceinline__ float bfbits(unsigned v) {
    union { unsigned u; float f; } c; c.u = v << 16; return c.f;
}
// dtype-agnostic scalar element load
__device__ __forceinline__ float ldf(const void* p, int idx, int isbf) {
    if (isbf) return bfbits(((const unsigned short*)p)[idx]);
    return ((const float*)p)[idx];
}
// Runtime dtype sniff. bf16 data: word bits[14:7] = exponent of a real value
// (<=124 for +-0.177 weights, <=133 for N(0,1) x). fp32 data: those bits are
// mantissa bits, uniform -> >=135 w.p. ~0.47/word. min(elems/2,64) words is
// in-bounds under EITHER interpretation. Deterministic on fixed dataset bits.
__device__ __forceinline__ int tensor_is_bf16(const void* p, int elems, int lane) {
    int nw = elems >> 1; if (nw > 64) nw = 64;
    int e = 0;
    if (lane < nw) {
        unsigned w = ((const unsigned*)p)[lane];
        e = (int)((w >> 7) & 0xFF);
    }
    return __ballot(e >= 135) == 0ULL;
}

// One wave per batch element. Lane j owns gate rows j and j+64 of each 128-row
// gate matrix: lane j<32 holds (i_j, g_j), lane j+32 holds (f_j, o_j).
// Packed float2 weights -> v_pk_fma_f32 (2 rows per instruction).
__global__ __launch_bounds__(64, 1)
void lstm_seq_kernel(const void* __restrict__ gx,
                     const void* __restrict__ gWih1,
                     const void* __restrict__ gWhh1,
                     const void* __restrict__ gbih1,
                     const void* __restrict__ gbhh1,
                     const void* __restrict__ gWih2,
                     const void* __restrict__ gWhh2,
                     const void* __restrict__ gbih2,
                     const void* __restrict__ gbhh2,
                     const void* __restrict__ gWlin,
                     const void* __restrict__ gblin,
                     float* __restrict__ gout,
                     int xelems)
{
    const int lane = threadIdx.x;
    const int b    = blockIdx.x;

    __shared__ __align__(16) float sh1[HID];
    __shared__ __align__(16) float sh2[HID];

    // ---- per-tensor dtype detection (wave-uniform, identical in all blocks) ----
    const int xbf  = tensor_is_bf16(gx,    xelems,    lane);
    const int w1bf = tensor_is_bf16(gWih1, 4*HID*DIN, lane);
    const int h1bf = tensor_is_bf16(gWhh1, 4*HID*HID, lane);
    const int a1bf = tensor_is_bf16(gbih1, 4*HID,     lane);
    const int c1bf = tensor_is_bf16(gbhh1, 4*HID,     lane);
    const int w2bf = tensor_is_bf16(gWih2, 4*HID*HID, lane);
    const int h2bf = tensor_is_bf16(gWhh2, 4*HID*HID, lane);
    const int a2bf = tensor_is_bf16(gbih2, 4*HID,     lane);
    const int c2bf = tensor_is_bf16(gbhh2, 4*HID,     lane);
    const int wlbf = tensor_is_bf16(gWlin, DOUT*HID,  lane);
    const int blbf = tensor_is_bf16(gblin, DOUT,      lane);

    const int r0 = lane;        // i (lane<32) / f (lane>=32)
    const int r1 = lane + 64;   // g (lane<32) / o (lane>=32)

    float ra[HID], rb[HID];
    auto load32 = [&](const void* W, int row, int isbf, float* dst) {
#pragma unroll
        for (int k = 0; k < HID; ++k) dst[k] = ldf(W, row * HID + k, isbf);
    };

    // ---- stage all weights into registers (fp32, float2-packed over rows) ----
    v2f wih1[DIN];
#pragma unroll
    for (int k = 0; k < DIN; ++k)
        wih1[k] = (v2f){ ldf(gWih1, r0 * DIN + k, w1bf),
                         ldf(gWih1, r1 * DIN + k, w1bf) };

    v2f whh1[HID], wih2[HID], whh2[HID], wlin[HID];
    load32(gWhh1, r0, h1bf, ra); load32(gWhh1, r1, h1bf, rb);
#pragma unroll
    for (int k = 0; k < HID; ++k) whh1[k] = (v2f){ ra[k], rb[k] };
    load32(gWih2, r0, w2bf, ra); load32(gWih2, r1, w2bf, rb);
#pragma unroll
    for (int k = 0; k < HID; ++k) wih2[k] = (v2f){ ra[k], rb[k] };
    load32(gWhh2, r0, h2bf, ra); load32(gWhh2, r1, h2bf, rb);
#pragma unroll
    for (int k = 0; k < HID; ++k) whh2[k] = (v2f){ ra[k], rb[k] };
    {
        int rlo = lane;                                  // rows 0..63
        int rhi = (lane < DOUT - 64) ? lane + 64 : lane; // rows 64..79 on lanes 0..15
        load32(gWlin, rlo, wlbf, ra); load32(gWlin, rhi, wlbf, rb);
#pragma unroll
        for (int k = 0; k < HID; ++k) wlin[k] = (v2f){ ra[k], rb[k] };
    }

    v2f bias1 = { ldf(gbih1, r0, a1bf) + ldf(gbhh1, r0, c1bf),
                  ldf(gbih1, r1, a1bf) + ldf(gbhh1, r1, c1bf) };
    v2f bias2 = { ldf(gbih2, r0, a2bf) + ldf(gbhh2, r0, c2bf),
                  ldf(gbih2, r1, a2bf) + ldf(gbhh2, r1, c2bf) };
    v2f biasl = { ldf(gblin, lane, blbf),
                  (lane < 16) ? ldf(gblin, lane + 64, blbf) : 0.0f };

    // x: 8 values per step, wave-uniform address; width depends on dtype
    const char* xbase = (const char*)gx +
        (size_t)b * TLEN * DIN * (xbf ? 2 : 4);
    auto load_x = [&](float* d, int t) {
        if (xbf) {
            uint4 u = ((const uint4*)xbase)[t];          // 8 bf16 = 16B
            d[0] = bfbits(u.x & 0xffffu); d[1] = bfbits(u.x >> 16);
            d[2] = bfbits(u.y & 0xffffu); d[3] = bfbits(u.y >> 16);
            d[4] = bfbits(u.z & 0xffffu); d[5] = bfbits(u.z >> 16);
            d[6] = bfbits(u.w & 0xffffu); d[7] = bfbits(u.w >> 16);
        } else {
            float4 a = ((const float4*)xbase)[2*t];      // 8 fp32 = 32B
            float4 c = ((const float4*)xbase)[2*t + 1];
            d[0] = a.x; d[1] = a.y; d[2] = a.z; d[3] = a.w;
            d[4] = c.x; d[5] = c.y; d[6] = c.z; d[7] = c.w;
        }
    };

    float* outp = gout + (size_t)b * TLEN * DOUT;

    float c1 = 0.0f, c2 = 0.0f;     // cell state for unit (lane) on lanes<32; garbage elsewhere (never read)
    v2f pre1 = (v2f){0.0f, 0.0f};   // Whh1 . h1_{t-1}
    v2f pre2 = (v2f){0.0f, 0.0f};   // Whh2 . h2_{t-1}
    float xc[DIN];
    load_x(xc, 0);

#pragma unroll 1
    for (int t = 0; t < TLEN; ++t) {
        // prefetch next x early so latency hides under the dependent chain
        float xn[DIN];
        if (t + 1 < TLEN) load_x(xn, t + 1);

        // ---- layer-1 gates = pre1 + bias + Wih1 . x_t ----
        v2f g1 = pre1 + bias1;
#pragma unroll
        for (int k = 0; k < DIN; ++k) { v2f s = { xc[k], xc[k] }; g1 += wih1[k] * s; }

        // ---- layer-1 cell update (lane j<32 owns unit j; f,o live on lane j+32) ----
        float f1 = __shfl_xor(g1.x, 32);
        float o1 = __shfl_xor(g1.y, 32);
        c1 = fsig(f1) * c1 + fsig(g1.x) * ftanh(g1.y);
        float h1n = fsig(o1) * ftanh(c1);
        if (lane < HID) sh1[lane] = h1n;
        __syncthreads();   // 1 wave: ~free; orders LDS write->read

        // ---- h1 broadcast round: feeds gates2 (Wih2) AND next-step pre1 (Whh1) ----
        v2f g2 = pre2 + bias2;
        pre1 = (v2f){0.0f, 0.0f};
#pragma unroll
        for (int q = 0; q < 8; ++q) {
            float4 hv = ((const float4*)sh1)[q];   // ds_read_b128, same-addr broadcast
            v2f s0 = { hv.x, hv.x }, s1 = { hv.y, hv.y };
            v2f s2 = { hv.z, hv.z }, s3 = { hv.w, hv.w };
            g2 += wih2[4*q+0] * s0;  pre1 += whh1[4*q+0] * s0;
            g2 += wih2[4*q+1] * s1;  pre1 += whh1[4*q+1] * s1;
            g2 += wih2[4*q+2] * s2;  pre1 += whh1[4*q+2] * s2;
            g2 += wih2[4*q+3] * s3;  pre1 += whh1[4*q+3] * s3;
        }

        // ---- layer-2 cell update ----
        float f2 = __shfl_xor(g2.x, 32);
        float o2 = __shfl_xor(g2.y, 32);
        c2 = fsig(f2) * c2 + fsig(g2.x) * ftanh(g2.y);
        float h2n = fsig(o2) * ftanh(c2);
        if (lane < HID) sh2[lane] = h2n;
        __syncthreads();

        // ---- h2 broadcast round: feeds output proj (Wlin) AND next-step pre2 (Whh2) ----
        v2f oacc = biasl;
        pre2 = (v2f){0.0f, 0.0f};
#pragma unroll
        for (int q = 0; q < 8; ++q) {
            float4 hv = ((const float4*)sh2)[q];
            v2f s0 = { hv.x, hv.x }, s1 = { hv.y, hv.y };
            v2f s2 = { hv.z, hv.z }, s3 = { hv.w, hv.w };
            oacc += wlin[4*q+0] * s0;  pre2 += whh2[4*q+0] * s0;
            oacc += wlin[4*q+1] * s1;  pre2 += whh2[4*q+1] * s1;
            oacc += wlin[4*q+2] * s2;  pre2 += whh2[4*q+2] * s2;
            oacc += wlin[4*q+3] * s3;  pre2 += whh2[4*q+3] * s3;
        }

        float* op = outp + (size_t)t * DOUT;
        op[lane] = oacc.x;                       // rows 0..63
        if (lane < 16) op[64 + lane] = oacc.y;   // rows 64..79

#pragma unroll
        for (int k = 0; k < DIN; ++k) xc[k] = xn[k];
    }
}

extern "C" void kernel_launch(void* const* d_in, const int* in_sizes, int n_in,
                              void* d_out, int out_size, void* d_ws, size_t ws_size,
                              hipStream_t stream)
{
    float* out = (float*)d_out;
    const int xelems = in_sizes[0];
    const int B = xelems / (TLEN * DIN);   // 256 (element count, dtype-independent)
    lstm_seq_kernel<<<B, 64, 0, stream>>>(d_in[0], d_in[1], d_in[2], d_in[3],
                                          d_in[4], d_in[5], d_in[6], d_in[7],
                                          d_in[8], d_in[9], d_in[10],
                                          out, xelems);
}